// Round 4
// baseline (248.855 us; speedup 1.0000x reference)
//
#include <hip/hip_runtime.h>

#define N1c 25000
#define N2c 5000
#define Dc 256
#define DOUTc 128
#define EPSc 1e-5f
#define NEGc 0.01f
#define CAPc 32            // bucket capacity; passing degree ~Poisson(3.2)

typedef __attribute__((ext_vector_type(8))) short short8;
typedef __attribute__((ext_vector_type(4))) float f32x4;

__device__ __forceinline__ ushort f2bf(float f) {
    unsigned u = __float_as_uint(f);
    u += 0x7fffu + ((u >> 16) & 1u);          // round-to-nearest-even
    return (ushort)(u >> 16);
}
__device__ __forceinline__ float bf2f(ushort u) {
    return __uint_as_float(((unsigned)u) << 16);
}
__device__ __forceinline__ int imin(int a, int b) { return a < b ? a : b; }
__device__ __forceinline__ int imax(int a, int b) { return a > b ? a : b; }

// ---- prep_fill: weight transpose + single-pass bucketed CSR + mask1 --------
__global__ __launch_bounds__(256) void prep_fill(
    const int* __restrict__ src0, const int* __restrict__ dst0, const int* __restrict__ val0,
    const int* __restrict__ src1, const int* __restrict__ dst1, const int* __restrict__ val1,
    const int* __restrict__ ts, const int* __restrict__ time_p, const int* __restrict__ itv_p,
    const float* __restrict__ W1l, const float* __restrict__ W1r,
    const float* __restrict__ W2l, const float* __restrict__ W2r,
    int E0, int E1,
    ushort* __restrict__ Bt1, ushort* __restrict__ Bt2,
    int* __restrict__ cnt0, int* __restrict__ cnt1,
    int* __restrict__ eidx0, int* __restrict__ eidx1,
    float* __restrict__ mask_out) {
    const int flat = blockIdx.x * blockDim.x + threadIdx.x;
    const int NT = gridDim.x * blockDim.x;
    const int t0 = *time_p, iv = *itv_p;

    for (int i = flat; i < 256 * 512; i += NT) {   // Bt1 [n][512]
        int n = i >> 9, k = i & 511;
        float v = (k < 256) ? W1l[(size_t)k * 256 + n] : W1r[(size_t)(k - 256) * 256 + n];
        Bt1[i] = f2bf(v);
    }
    for (int i = flat; i < 128 * 512; i += NT) {   // Bt2 [n][512]
        int n = i >> 9, k = i & 511;
        float v = (k < 256) ? W2l[(size_t)k * 128 + n] : W2r[(size_t)(k - 256) * 128 + n];
        Bt2[i] = f2bf(v);
    }
    for (int e = flat; e < E0; e += NT) {
        int t = ts[val0[e]];
        if (t >= t0 && t < t0 + iv) {
            int d = dst0[e];
            int pos = atomicAdd(&cnt0[d], 1);
            if (pos < CAPc) eidx0[d * CAPc + pos] = src0[e];
        }
    }
    for (int e = flat; e < E1; e += NT) {
        int t = ts[val1[e]];
        bool m = (t >= t0 && t < t0 + iv);
        mask_out[e] = m ? 1.0f : 0.0f;
        if (m) {
            int d = dst1[e];
            int pos = atomicAdd(&cnt1[d], 1);
            if (pos < CAPc) eidx1[d * CAPc + pos] = src1[e];
        }
    }
}

// ---- fused gather + GEMM, 8-wave blocks, MLP-optimized gather --------------
// Phase 1 restructured for memory-level parallelism:
//   RT1: cnt loads for all RPW rows issued together.
//   RT2: eidx + root-row loads for all rows issued together.
//   RT3+: rows processed in PAIRS; each pair issues a 4-wide predicated load
//         batch for BOTH rows (8 independent row-loads in flight) before
//         accumulating. shfl slot indices are clamped (my sanitized to 0 for
//         lanes >= c) so loads are always address-safe without branches.
// Phase 2: barrier-free k-loop, A from LDS, B direct from L2-resident Bt.
// VARIANT 0: gather/root from fp32 x, out = bf16 h with BN+leaky epilogue.
// VARIANT 1: gather/root from bf16 h, out = fp32 + bias.
template <int VARIANT, int BMT, int NJW>
__global__ __launch_bounds__(512) void fused_gemm(
    const void* __restrict__ Asrc,
    const int* __restrict__ cnt, const int* __restrict__ eidx,
    const int* __restrict__ src, const int* __restrict__ dst,
    const int* __restrict__ val, const int* __restrict__ ts,
    const int* __restrict__ time_p, const int* __restrict__ itv_p, int E,
    const ushort* __restrict__ Bt,
    const float* __restrict__ bias,
    const float* __restrict__ g, const float* __restrict__ bt,
    const float* __restrict__ rm, const float* __restrict__ rv,
    void* __restrict__ Cout, int M) {
    constexpr int RT = BMT / 16;          // row-tiles per block
    constexpr int RPW = BMT / 8;          // gather rows per wave (even)
    __shared__ ushort As[BMT][536];
    const int tid = threadIdx.x;
    const int wave = tid >> 6, lane = tid & 63;
    const int quad = lane >> 4, l16 = lane & 15;
    const int m0 = blockIdx.x * BMT;
    const float* Xf = (const float*)Asrc;
    const ushort* Hb = (const ushort*)Asrc;

    // ---------------- phase 1: gather RPW rows per wave ----------------
    int ms_[RPW], cs_[RPW], my_[RPW];
#pragma unroll
    for (int i = 0; i < RPW; ++i) {               // RT1: all cnt loads together
        ms_[i] = m0 + wave * RPW + i;
        cs_[i] = (ms_[i] < M) ? cnt[ms_[i]] : 0;
    }
#pragma unroll
    for (int i = 0; i < RPW; ++i)                 // RT2a: all eidx loads together
        my_[i] = (ms_[i] < M && lane < CAPc) ? eidx[ms_[i] * CAPc + lane] : 0;
    float4 rtf_[RPW];
    ushort4 rtb_[RPW];
#pragma unroll
    for (int i = 0; i < RPW; ++i) {               // RT2b: all root loads together
        int mm = imax(0, imin(ms_[i], M - 1));
        if (VARIANT == 0) rtf_[i] = *(const float4*)(Xf + (size_t)mm * Dc + lane * 4);
        else              rtb_[i] = *(const ushort4*)(Hb + (size_t)mm * Dc + lane * 4);
    }
#pragma unroll
    for (int i = 0; i < RPW; ++i)                 // sanitize: clamped shfl slots -> row 0
        my_[i] = (lane < cs_[i]) ? my_[i] : 0;

    float4 acc_[RPW];
#pragma unroll
    for (int i = 0; i < RPW; ++i) acc_[i] = make_float4(0.f, 0.f, 0.f, 0.f);

#pragma unroll
    for (int p = 0; p < RPW; p += 2) {
        float4 vf[2][4];
        ushort4 vb[2][4];
        int ccs[2];
        // ---- issue first 4-wide batch for BOTH rows of the pair ----
#pragma unroll
        for (int q = 0; q < 2; ++q) {
            int cc = imin(cs_[p + q], CAPc);
            ccs[q] = cc;
#pragma unroll
            for (int u = 0; u < 4; ++u) {
                int e = imax(0, imin(u, cc - 1));
                int s = __shfl(my_[p + q], e, 64);
                if (VARIANT == 0) vf[q][u] = *(const float4*)(Xf + (size_t)s * Dc + lane * 4);
                else              vb[q][u] = *(const ushort4*)(Hb + (size_t)s * Dc + lane * 4);
            }
        }
        // ---- accumulate (predicated), then rare tail batches ----
#pragma unroll
        for (int q = 0; q < 2; ++q) {
            int i = p + q;
            int cc = ccs[q];
#pragma unroll
            for (int u = 0; u < 4; ++u) {
                if (u < cc) {
                    if (VARIANT == 0) {
                        acc_[i].x += vf[q][u].x; acc_[i].y += vf[q][u].y;
                        acc_[i].z += vf[q][u].z; acc_[i].w += vf[q][u].w;
                    } else {
                        acc_[i].x += bf2f(vb[q][u].x); acc_[i].y += bf2f(vb[q][u].y);
                        acc_[i].z += bf2f(vb[q][u].z); acc_[i].w += bf2f(vb[q][u].w);
                    }
                }
            }
            for (int jb = 4; jb < cc; jb += 4) {  // tail: c>4 (rare)
#pragma unroll
                for (int u = 0; u < 4; ++u) {
                    int e = imin(jb + u, cc - 1);
                    int s = __shfl(my_[i], e, 64);
                    if (jb + u < cc) {
                        if (VARIANT == 0) {
                            float4 v = *(const float4*)(Xf + (size_t)s * Dc + lane * 4);
                            acc_[i].x += v.x; acc_[i].y += v.y; acc_[i].z += v.z; acc_[i].w += v.w;
                        } else {
                            ushort4 v = *(const ushort4*)(Hb + (size_t)s * Dc + lane * 4);
                            acc_[i].x += bf2f(v.x); acc_[i].y += bf2f(v.y);
                            acc_[i].z += bf2f(v.z); acc_[i].w += bf2f(v.w);
                        }
                    }
                }
            }
        }
    }
    // overflow fallback (statistically never taken; keeps any input correct)
#pragma unroll
    for (int i = 0; i < RPW; ++i) {
        if (cs_[i] > CAPc) {
            float4 a = make_float4(0.f, 0.f, 0.f, 0.f);
            int t0 = *time_p, iv = *itv_p;
            for (int e = 0; e < E; ++e) {
                if (dst[e] != ms_[i]) continue;
                int t = ts[val[e]];
                if (t >= t0 && t < t0 + iv) {
                    if (VARIANT == 0) {
                        float4 v = *(const float4*)(Xf + (size_t)src[e] * Dc + lane * 4);
                        a.x += v.x; a.y += v.y; a.z += v.z; a.w += v.w;
                    } else {
                        ushort4 v = *(const ushort4*)(Hb + (size_t)src[e] * Dc + lane * 4);
                        a.x += bf2f(v.x); a.y += bf2f(v.y); a.z += bf2f(v.z); a.w += bf2f(v.w);
                    }
                }
            }
            acc_[i] = a;
        }
    }
    // ---- write LDS: mean + root ----
#pragma unroll
    for (int i = 0; i < RPW; ++i) {
        int r = wave * RPW + i;
        if (ms_[i] >= M) {
            *(ushort4*)&As[r][lane * 4] = make_ushort4(0, 0, 0, 0);
            *(ushort4*)&As[r][256 + lane * 4] = make_ushort4(0, 0, 0, 0);
            continue;
        }
        float inv = 1.0f / fmaxf((float)cs_[i], 1.0f);
        ushort4 o;
        o.x = f2bf(acc_[i].x * inv); o.y = f2bf(acc_[i].y * inv);
        o.z = f2bf(acc_[i].z * inv); o.w = f2bf(acc_[i].w * inv);
        *(ushort4*)&As[r][lane * 4] = o;
        if (VARIANT == 0) {
            ushort4 ro;
            ro.x = f2bf(rtf_[i].x); ro.y = f2bf(rtf_[i].y);
            ro.z = f2bf(rtf_[i].z); ro.w = f2bf(rtf_[i].w);
            *(ushort4*)&As[r][256 + lane * 4] = ro;
        } else {
            *(ushort4*)&As[r][256 + lane * 4] = rtb_[i];
        }
    }
    __syncthreads();

    // ---------------- phase 2: barrier-free MFMA k-loop ----------------
    f32x4 acc[RT][NJW] = {};
    const ushort* Bw = Bt + (size_t)((wave * NJW) * 16 + l16) * 512 + quad * 8;
    for (int k0 = 0; k0 < 512; k0 += 32) {
        short8 af[RT];
#pragma unroll
        for (int rt = 0; rt < RT; ++rt)
            af[rt] = *(const short8*)&As[rt * 16 + l16][k0 + quad * 8];
        uint4 bfr[NJW];
#pragma unroll
        for (int jj = 0; jj < NJW; ++jj)
            bfr[jj] = *(const uint4*)(Bw + (size_t)jj * 16 * 512 + k0);
#pragma unroll
        for (int jj = 0; jj < NJW; ++jj) {
            short8 bf = *reinterpret_cast<const short8*>(&bfr[jj]);
#pragma unroll
            for (int rt = 0; rt < RT; ++rt)
                acc[rt][jj] = __builtin_amdgcn_mfma_f32_16x16x32_bf16(af[rt], bf, acc[rt][jj], 0, 0, 0);
        }
    }

    // ---------------- epilogue: C/D layout col=l16, row=quad*4+reg -----
#pragma unroll
    for (int jj = 0; jj < NJW; ++jj) {
        int gn = (wave * NJW + jj) * 16 + l16;
        float sc = 1.f, sh = bias[gn];
        if (VARIANT == 0) {
            float s = g[gn] * rsqrtf(rv[gn] + EPSc);
            sh = (bias[gn] - rm[gn]) * s + bt[gn];
            sc = s;
        }
#pragma unroll
        for (int rt = 0; rt < RT; ++rt) {
            int gmb = m0 + rt * 16 + quad * 4;
#pragma unroll
            for (int rr = 0; rr < 4; ++rr) {
                int gm = gmb + rr;
                if (gm >= M) continue;
                float v = acc[rt][jj][rr];
                if (VARIANT == 0) {
                    v = v * sc + sh;
                    v = v >= 0.f ? v : NEGc * v;
                    ((ushort*)Cout)[(size_t)gm * Dc + gn] = f2bf(v);
                } else {
                    ((float*)Cout)[(size_t)gm * DOUTc + gn] = v + sh;
                }
            }
        }
    }
}

extern "C" void kernel_launch(void* const* d_in, const int* in_sizes, int n_in,
                              void* d_out, int out_size, void* d_ws, size_t ws_size,
                              hipStream_t stream) {
    const float* x    = (const float*)d_in[0];
    const int* src0   = (const int*)d_in[1];
    const int* dst0   = (const int*)d_in[2];
    const int* val0   = (const int*)d_in[3];
    const int* src1   = (const int*)d_in[4];
    const int* dst1   = (const int*)d_in[5];
    const int* val1   = (const int*)d_in[6];
    const int* ts     = (const int*)d_in[7];
    const int* time_p = (const int*)d_in[8];
    const int* itv_p  = (const int*)d_in[9];
    const float* W1l  = (const float*)d_in[10];
    const float* W1r  = (const float*)d_in[11];
    const float* b1   = (const float*)d_in[12];
    const float* g1   = (const float*)d_in[13];
    const float* bt1  = (const float*)d_in[14];
    const float* rm1  = (const float*)d_in[15];
    const float* rv1  = (const float*)d_in[16];
    const float* W2l  = (const float*)d_in[17];
    const float* W2r  = (const float*)d_in[18];
    const float* b2   = (const float*)d_in[19];
    int E0 = in_sizes[1];
    int E1 = in_sizes[4];
    float* out = (float*)d_out;

    // ---- workspace layout ----
    ushort* h    = (ushort*)d_ws;                  // [N1][256] bf16
    ushort* Bt1  = h    + (size_t)N1c * Dc;        // [256][512]
    ushort* Bt2  = Bt1  + 256 * 512;               // [128][512]
    int* ip      = (int*)(Bt2 + 128 * 512);
    int* cnt0    = ip;             ip += N1c;      // -- zeroed (memset)
    int* cnt1    = ip;             ip += N2c;      // -- zeroed (memset)
    int* eidx0   = ip;             ip += N1c * CAPc;
    int* eidx1   = ip;             ip += N2c * CAPc;
    float* mask_tail = out + (size_t)N2c * DOUTc;

    hipMemsetAsync(cnt0, 0, (size_t)(N1c + N2c) * sizeof(int), stream);

    prep_fill<<<2048, 256, 0, stream>>>(
        src0, dst0, val0, src1, dst1, val1, ts, time_p, itv_p,
        W1l, W1r, W2l, W2r, E0, E1, Bt1, Bt2,
        cnt0, cnt1, eidx0, eidx1, mask_tail);
    fused_gemm<0, 32, 2><<<(N1c + 31) / 32, 512, 0, stream>>>(
        x, cnt0, eidx0, src0, dst0, val0, ts, time_p, itv_p, E0,
        Bt1, b1, g1, bt1, rm1, rv1, h, N1c);
    fused_gemm<1, 16, 1><<<(N2c + 15) / 16, 512, 0, stream>>>(
        h, cnt1, eidx1, src1, dst1, val1, ts, time_p, itv_p, E1,
        Bt2, b2, nullptr, nullptr, nullptr, nullptr, out, N2c);
}